// Round 4
// baseline (244.745 us; speedup 1.0000x reference)
//
#include <hip/hip_runtime.h>
#include <cstdint>

// ---------- types ----------
typedef unsigned short u16;
typedef __bf16 bf16;
typedef bf16 bf16x8 __attribute__((ext_vector_type(8)));
typedef float f32x4 __attribute__((ext_vector_type(4)));
typedef u16 u16x4 __attribute__((ext_vector_type(4)));
typedef u16 u16x8 __attribute__((ext_vector_type(8)));

#define B_SZ 4
#define L_SZ 1024
#define DM 512
#define DIN 1024
#define NST 16
#define RR 32
#define KC 4
#define NCHUNK 16
#define LC 64

__device__ __forceinline__ u16 f2bf(float f) {
  union { float f; uint32_t u; } v; v.f = f;
  uint32_t r = (v.u + 0x7FFFu + ((v.u >> 16) & 1u)) >> 16;
  return (u16)r;
}
__device__ __forceinline__ float bf2f(u16 h) {
  union { uint32_t u; float f; } v; v.u = ((uint32_t)h) << 16;
  return v.f;
}

// hardware 2^x (v_exp_f32), arg pre-scaled by log2(e) where needed
__device__ __forceinline__ float exp2i(float x) {
#if __has_builtin(__builtin_amdgcn_exp2f)
  return __builtin_amdgcn_exp2f(x);
#else
  float r; asm("v_exp_f32 %0, %1" : "=v"(r) : "v"(x)); return r;
#endif
}

// DPP cross-lane add on the VALU pipe (no LDS). CTRL: 0xB1=quad_perm(1,0,3,2)
// (xor1), 0x4E=quad_perm(2,3,0,1) (xor2), 0x124=row_ror:4, 0x128=row_ror:8.
// Rotations within a 16-lane row are sum-complete after {1,2}-xor + {4,8}-ror.
template <int CTRL>
__device__ __forceinline__ float dpp_add(float x) {
  int xi = __builtin_bit_cast(int, x);
  int yi = __builtin_amdgcn_update_dpp(0, xi, CTRL, 0xF, 0xF, false);
  return x + __builtin_bit_cast(float, yi);
}

__device__ __forceinline__ void gload16(const void* g, void* l) {
  __builtin_amdgcn_global_load_lds(
      (const __attribute__((address_space(1))) unsigned int*)g,
      (__attribute__((address_space(3))) unsigned int*)l, 16, 0, 0);
}

// ---------- f32 -> bf16 convert ----------
__launch_bounds__(256)
__global__ void cvt_f2b(const float* __restrict__ in, u16* __restrict__ out, int n) {
  int i = (blockIdx.x * 256 + threadIdx.x) * 8;
  if (i >= n) return;
  f32x4 a = *(const f32x4*)(in + i);
  f32x4 b = *(const f32x4*)(in + i + 4);
  u16x8 o;
#pragma unroll
  for (int j = 0; j < 4; j++) { o[j] = f2bf(a[j]); o[4 + j] = f2bf(b[j]); }
  *(u16x8*)(out + i) = o;
}

// ---------- f32 (R x C) -> bf16 transpose (C x R) ----------
__global__ void transpose_f2b(const float* __restrict__ in, u16* __restrict__ out,
                              int R, int C) {
  __shared__ float tile[32][33];
  int tx = threadIdx.x, ty = threadIdx.y;
  int c0 = blockIdx.x * 32, r0 = blockIdx.y * 32;
#pragma unroll
  for (int i = 0; i < 4; i++)
    tile[ty + i * 8][tx] = in[(long)(r0 + ty + i * 8) * C + c0 + tx];
  __syncthreads();
#pragma unroll
  for (int i = 0; i < 4; i++)
    out[(long)(c0 + ty + i * 8) * R + r0 + tx] = f2bf(tile[tx][ty + i * 8]);
}

// ---------- templated bf16 MFMA GEMM: C = A(MxK) * Bt(NxK)^T ----------
// EPI 0: f32 out (+bias), 1: bf16 out, 2: softplus(acc+bias) f32 out
template <int BM, int BN, int BK, int EPI>
__launch_bounds__(256, 2)
__global__ void gemm_bf16(const bf16* __restrict__ A, int lda,
                          const bf16* __restrict__ Bt, int ldb,
                          void* __restrict__ Cv, int ldc,
                          const float* __restrict__ bias, int K) {
  constexpr int WM = BM / 2, WN = BN / 2;
  constexpr int MF = WM / 16, NF = WN / 16;
  constexpr int LPR = BK / 8;            // 16B lanes per tile row
  constexpr int AISS = (BM * BK * 2) / 4096;
  constexpr int BISS = (BN * BK * 2) / 4096;
  __shared__ bf16 As[BM * BK];
  __shared__ bf16 Bs[BN * BK];
  const int t = threadIdx.x;
  const int lane = t & 63;
  const int wid = t >> 6;
  const int wm = wid >> 1, wn = wid & 1;
  const int r = lane & 15, kg = lane >> 4;
  const long row0 = (long)blockIdx.x * BM, col0 = (long)blockIdx.y * BN;

  f32x4 acc[MF][NF];
#pragma unroll
  for (int m = 0; m < MF; m++)
#pragma unroll
    for (int n = 0; n < NF; n++) acc[m][n] = f32x4{0.f, 0.f, 0.f, 0.f};

  for (int k0 = 0; k0 < K; k0 += BK) {
    __syncthreads();
#pragma unroll
    for (int i = 0; i < AISS; i++) {
      int slot = i * 256 + t;
      int rw = slot / LPR, lc = slot % LPR;
      gload16(A + (row0 + rw) * lda + k0 + lc * 8,
              (char*)As + i * 4096 + wid * 1024);
    }
#pragma unroll
    for (int i = 0; i < BISS; i++) {
      int slot = i * 256 + t;
      int rw = slot / LPR, lc = slot % LPR;
      gload16(Bt + (col0 + rw) * ldb + k0 + lc * 8,
              (char*)Bs + i * 4096 + wid * 1024);
    }
    __syncthreads();
#pragma unroll
    for (int kk = 0; kk < BK / 32; kk++) {
      bf16x8 av[MF], bv[NF];
#pragma unroll
      for (int m = 0; m < MF; m++)
        av[m] = *(const bf16x8*)&As[(wm * WM + m * 16 + r) * BK + kk * 32 + kg * 8];
#pragma unroll
      for (int n = 0; n < NF; n++)
        bv[n] = *(const bf16x8*)&Bs[(wn * WN + n * 16 + r) * BK + kk * 32 + kg * 8];
#pragma unroll
      for (int m = 0; m < MF; m++)
#pragma unroll
        for (int n = 0; n < NF; n++)
          acc[m][n] = __builtin_amdgcn_mfma_f32_16x16x32_bf16(av[m], bv[n], acc[m][n], 0, 0, 0);
    }
  }

#pragma unroll
  for (int m = 0; m < MF; m++) {
    const long grow0 = row0 + wm * WM + m * 16 + kg * 4;
#pragma unroll
    for (int n = 0; n < NF; n++) {
      const long gcol = col0 + wn * WN + n * 16 + r;
      float bval = bias ? bias[gcol] : 0.f;
#pragma unroll
      for (int j = 0; j < 4; j++) {
        float v = acc[m][n][j] + bval;
        long idx = (grow0 + j) * ldc + gcol;
        if (EPI == 0) {
          ((float*)Cv)[idx] = v;
        } else if (EPI == 1) {
          ((u16*)Cv)[idx] = f2bf(v);
        } else {
          ((float*)Cv)[idx] = (v > 20.f) ? v : log1pf(__expf(v));
        }
      }
    }
  }
}

// ---------- depthwise causal conv (K=4) + SiLU ----------
__launch_bounds__(256)
__global__ void conv_silu_k(const u16* __restrict__ xr, const float* __restrict__ cw,
                            const float* __restrict__ cb, u16* __restrict__ u) {
  int tid = blockIdx.x * 256 + threadIdx.x;
  int dblk = tid & 127, row = tid >> 7;     // row = b*L + l
  int l = row & (L_SZ - 1);
  int d = dblk * 8;
  float xv[4][8];
#pragma unroll
  for (int k = 0; k < 4; k++) {
    int ls = l - 3 + k;
    if (ls < 0) {
#pragma unroll
      for (int j = 0; j < 8; j++) xv[k][j] = 0.f;
    } else {
      u16x8 vv = *(const u16x8*)(xr + (long)(row - 3 + k) * (2 * DIN) + d);
#pragma unroll
      for (int j = 0; j < 8; j++) xv[k][j] = bf2f(vv[j]);
    }
  }
  u16x8 ov;
#pragma unroll
  for (int j = 0; j < 8; j++) {
    f32x4 w = *(const f32x4*)(cw + (d + j) * 4);
    float acc = cb[d + j] + w[0] * xv[0][j] + w[1] * xv[1][j] + w[2] * xv[2][j] + w[3] * xv[3][j];
    float s = acc / (1.f + __expf(-acc));
    ov[j] = f2bf(s);
  }
  *(u16x8*)(u + (long)row * DIN + d) = ov;
}

// ---------- selective scan, chunked ----------
// Block covers 32 d x 16 n for one (b, chunk); each thread runs TWO
// independent recurrence chains (d = d0+dl and d0+16+dl) so fma/exp latency
// of one chain hides under the other (paired float ops -> v_pk_* eligible).
// exp folded to hardware 2^x: An2 = -exp(A_log)*log2(e).
// LDS d/n-major [.][68] rows: inner reads are f32x4 wave-broadcasts, rows
// r/r+8 share a bank quad (2-way = free).
// Phase A (WITHY=0): local end state + exp2(An2*sum(delta)) decay product.
// Phase C (WITHY=1): replay with true s_init; y-reduction over n via DPP;
// +u*D and silu(res) gating fused in the epilogue (u re-read from global).
template <int WITHY>
__launch_bounds__(256, 4)
__global__ void scan_phase(const float* __restrict__ delta, const u16* __restrict__ u,
                           const u16* __restrict__ xdbl, const float* __restrict__ A_log,
                           const float* __restrict__ s_init, const float* __restrict__ Dvec,
                           const u16* __restrict__ xr,
                           float* __restrict__ S_end, float* __restrict__ P,
                           u16* __restrict__ yg) {
  int bi = blockIdx.x;
  int dg = bi & 31, rem = bi >> 5;
  int chunk = rem & (NCHUNK - 1), b = rem >> 4;
  int d0 = dg * 32, l0 = chunk * LC;
  __shared__ float sdt[32][68];
  __shared__ float sdu[32][68];
  __shared__ float sBt[16][68];
  __shared__ float sCt[WITHY ? 16 : 1][WITHY ? 68 : 1];
  __shared__ float syy[WITHY ? LC : 1][WITHY ? 36 : 1];
  const int t = threadIdx.x;
  const int n = t & 15, dl = t >> 4;
  const int da = d0 + dl, db = da + 16;
  const long sidxa = ((long)(b * NCHUNK + chunk) * DIN + da) * NST + n;
  const long sidxb = sidxa + 16 * NST;
  const float L2E = 1.44269504088896f;
  float Ana = -__expf(A_log[da * NST + n]) * L2E;
  float Anb = -__expf(A_log[db * NST + n]) * L2E;
  float sa = 0.f, sb = 0.f;
  if constexpr (WITHY) { sa = s_init[sidxa]; sb = s_init[sidxb]; }
  {
    const int lr = t >> 2, c4 = (t & 3) * 4;
    const long rowb = (long)b * L_SZ + l0 + lr;
#pragma unroll
    for (int h = 0; h < 2; h++) {
      const int dc = c4 + 16 * h;
      f32x4 dd = *(const f32x4*)(delta + rowb * DIN + d0 + dc);
      u16x4 uu = *(const u16x4*)(u + rowb * DIN + d0 + dc);
#pragma unroll
      for (int j = 0; j < 4; j++) {
        sdt[dc + j][lr] = dd[j];
        sdu[dc + j][lr] = dd[j] * bf2f(uu[j]);
      }
    }
    u16x4 bb = *(const u16x4*)(xdbl + rowb * 64 + RR + c4);
#pragma unroll
    for (int j = 0; j < 4; j++) sBt[c4 + j][lr] = bf2f(bb[j]);
    if constexpr (WITHY) {
      u16x4 cc = *(const u16x4*)(xdbl + rowb * 64 + RR + NST + c4);
#pragma unroll
      for (int j = 0; j < 4; j++) sCt[c4 + j][lr] = bf2f(cc[j]);
    }
  }
  __syncthreads();

  const float* dra = &sdt[dl][0];
  const float* drb = &sdt[dl + 16][0];
  const float* ura = &sdu[dl][0];
  const float* urb = &sdu[dl + 16][0];
  const float* bro = &sBt[n][0];
  const float* cro = WITHY ? &sCt[n][0] : (const float*)nullptr;

  f32x4 deA = *(const f32x4*)dra, deB = *(const f32x4*)drb;
  f32x4 duA = *(const f32x4*)ura, duB = *(const f32x4*)urb;
  f32x4 bv4 = *(const f32x4*)bro;
  f32x4 cv4{};
  if constexpr (WITHY) cv4 = *(const f32x4*)cro;
  float sdaa = 0.f, sdab = 0.f;
#pragma unroll
  for (int lb = 0; lb < LC; lb += 4) {
    f32x4 deA2{}, deB2{}, duA2{}, duB2{}, bv42{}, cv42{};
    if (lb + 4 < LC) {
      deA2 = *(const f32x4*)(dra + lb + 4);
      deB2 = *(const f32x4*)(drb + lb + 4);
      duA2 = *(const f32x4*)(ura + lb + 4);
      duB2 = *(const f32x4*)(urb + lb + 4);
      bv42 = *(const f32x4*)(bro + lb + 4);
      if constexpr (WITHY) cv42 = *(const f32x4*)(cro + lb + 4);
    }
#pragma unroll
    for (int jj = 0; jj < 4; jj++) {
      float ea = deA[jj] * Ana;             // pk-eligible pair
      float eb = deB[jj] * Anb;
      float aa = exp2i(ea);
      float ab = exp2i(eb);
      float bua = duA[jj] * bv4[jj];
      float bub = duB[jj] * bv4[jj];
      sa = fmaf(aa, sa, bua);
      sb = fmaf(ab, sb, bub);
      if constexpr (WITHY) {
        float y0 = sa * cv4[jj];
        float y1 = sb * cv4[jj];
        y0 = dpp_add<0xB1>(y0);  y1 = dpp_add<0xB1>(y1);
        y0 = dpp_add<0x4E>(y0);  y1 = dpp_add<0x4E>(y1);
        y0 = dpp_add<0x124>(y0); y1 = dpp_add<0x124>(y1);
        y0 = dpp_add<0x128>(y0); y1 = dpp_add<0x128>(y1);
        if (n == 0) {
          syy[lb + jj][dl] = y0;
          syy[lb + jj][dl + 16] = y1;
        }
      } else {
        sdaa += deA[jj];
        sdab += deB[jj];
      }
    }
    deA = deA2; deB = deB2; duA = duA2; duB = duB2; bv4 = bv42;
    if constexpr (WITHY) cv4 = cv42;
  }
  if constexpr (!WITHY) {
    S_end[sidxa] = sa;
    S_end[sidxb] = sb;
    P[sidxa] = exp2i(Ana * sdaa);
    P[sidxb] = exp2i(Anb * sdab);
  } else {
    __syncthreads();
    const int lr = t >> 2, c4 = (t & 3) * 4;
    const long rowb = (long)b * L_SZ + l0 + lr;
#pragma unroll
    for (int h = 0; h < 2; h++) {
      const int dc = c4 + 16 * h;
      f32x4 yv = *(const f32x4*)&syy[lr][dc];
      u16x4 uu = *(const u16x4*)(u + rowb * DIN + d0 + dc);
      f32x4 dv = *(const f32x4*)(Dvec + d0 + dc);
      u16x4 rr = *(const u16x4*)(xr + rowb * (2 * DIN) + DIN + d0 + dc);
      u16x4 og;
#pragma unroll
      for (int j = 0; j < 4; j++) {
        float res = bf2f(rr[j]);
        float sil = res / (1.f + __expf(-res));
        og[j] = f2bf((yv[j] + bf2f(uu[j]) * dv[j]) * sil);
      }
      *(u16x4*)(yg + rowb * DIN + d0 + dc) = og;
    }
  }
}

__launch_bounds__(256)
__global__ void scan_combine(const float* __restrict__ P, const float* __restrict__ S_end,
                             float* __restrict__ s_init) {
  int g = blockIdx.x * 256 + threadIdx.x;   // (b, d, n) : 4*1024*16
  int b = g >> 14, dn = g & 16383;
  long base = (long)b * (NCHUNK * DIN * NST) + dn;
  float s = 0.f;
#pragma unroll
  for (int c = 0; c < NCHUNK; c++) {
    long idx = base + (long)c * (DIN * NST);
    s_init[idx] = s;
    s = P[idx] * s + S_end[idx];
  }
}

// ---------- host ----------
extern "C" void kernel_launch(void* const* d_in, const int* in_sizes, int n_in,
                              void* d_out, int out_size, void* d_ws, size_t ws_size,
                              hipStream_t stream) {
  const float* x      = (const float*)d_in[0];
  const float* W_in   = (const float*)d_in[1];
  const float* conv_w = (const float*)d_in[2];
  const float* conv_b = (const float*)d_in[3];
  const float* W_x    = (const float*)d_in[4];
  const float* W_dt   = (const float*)d_in[5];
  const float* b_dt   = (const float*)d_in[6];
  const float* A_log  = (const float*)d_in[7];
  const float* Dvec   = (const float*)d_in[8];
  const float* W_out  = (const float*)d_in[9];
  const float* b_out  = (const float*)d_in[10];
  float* out = (float*)d_out;

  char* ws = (char*)d_ws;
  size_t off = 0;
  auto alloc = [&](size_t bytes) -> void* {
    void* p = ws + off;
    off += (bytes + 255) & ~(size_t)255;
    return p;
  };
  const int M = B_SZ * L_SZ;                  // 4096
  u16*   xw    = (u16*)alloc((size_t)M * DM * 2);
  u16*   winT  = (u16*)alloc((size_t)(2 * DIN) * DM * 2);
  u16*   xr    = (u16*)alloc((size_t)M * (2 * DIN) * 2);
  u16*   ubuf  = (u16*)alloc((size_t)M * DIN * 2);
  u16*   wxT   = (u16*)alloc((size_t)64 * DIN * 2);
  u16*   xdbl  = (u16*)alloc((size_t)M * 64 * 2);
  u16*   wdtT  = (u16*)alloc((size_t)DIN * RR * 2);
  float* delta = (float*)alloc((size_t)M * DIN * 4);
  float* Send  = (float*)alloc((size_t)B_SZ * NCHUNK * DIN * NST * 4);
  float* Pbuf  = (float*)alloc((size_t)B_SZ * NCHUNK * DIN * NST * 4);
  float* sini  = (float*)alloc((size_t)B_SZ * NCHUNK * DIN * NST * 4);
  u16*   yg    = (u16*)alloc((size_t)M * DIN * 2);
  u16*   woutT = (u16*)alloc((size_t)DM * DIN * 2);
  (void)ws_size; (void)in_sizes; (void)n_in; (void)out_size;

  // convert x to bf16
  cvt_f2b<<<(M * DM) / (256 * 8), 256, 0, stream>>>(x, xw, M * DM);
  // transpose weights to (N x K) bf16
  transpose_f2b<<<dim3((2 * DIN) / 32, DM / 32), dim3(32, 8), 0, stream>>>(W_in, winT, DM, 2 * DIN);
  transpose_f2b<<<dim3(64 / 32, DIN / 32), dim3(32, 8), 0, stream>>>(W_x, wxT, DIN, 64);
  transpose_f2b<<<dim3(DIN / 32, RR / 32), dim3(32, 8), 0, stream>>>(W_dt, wdtT, RR, DIN);
  transpose_f2b<<<dim3(DM / 32, DIN / 32), dim3(32, 8), 0, stream>>>(W_out, woutT, DIN, DM);

  // GEMM1: x_and_res = x @ W_in   (4096 x 2048, K=512) -> bf16
  gemm_bf16<128, 128, 64, 1><<<dim3(M / 128, (2 * DIN) / 128), 256, 0, stream>>>(
      (const bf16*)xw, DM, (const bf16*)winT, DM, xr, 2 * DIN, nullptr, DM);
  // conv + silu -> u (bf16)
  conv_silu_k<<<(M * DIN / 8) / 256, 256, 0, stream>>>(xr, conv_w, conv_b, ubuf);
  // GEMM2: x_dbl = u @ W_x  (4096 x 64, K=1024) -> bf16  (BM=32: 128 blocks)
  gemm_bf16<32, 64, 64, 1><<<dim3(M / 32, 1), 256, 0, stream>>>(
      (const bf16*)ubuf, DIN, (const bf16*)wxT, DIN, xdbl, 64, nullptr, DIN);
  // GEMM3: delta = softplus(x_dbl[:, :32] @ W_dt + b_dt) (4096 x 1024, K=32) -> f32
  gemm_bf16<128, 128, 32, 2><<<dim3(M / 128, DIN / 128), 256, 0, stream>>>(
      (const bf16*)xdbl, 64, (const bf16*)wdtT, RR, delta, DIN, b_dt, RR);
  // scan
  scan_phase<0><<<B_SZ * NCHUNK * (DIN / 32), 256, 0, stream>>>(
      delta, ubuf, xdbl, A_log, nullptr, nullptr, nullptr, Send, Pbuf, nullptr);
  scan_combine<<<(B_SZ * DIN * NST) / 256, 256, 0, stream>>>(Pbuf, Send, sini);
  scan_phase<1><<<B_SZ * NCHUNK * (DIN / 32), 256, 0, stream>>>(
      delta, ubuf, xdbl, A_log, sini, Dvec, xr, nullptr, nullptr, yg);
  // GEMM4: out = (y * silu(res)) @ W_out + b_out  (4096 x 512, K=1024) -> f32
  gemm_bf16<128, 64, 64, 0><<<dim3(M / 128, DM / 64), 256, 0, stream>>>(
      (const bf16*)yg, DIN, (const bf16*)woutT, DIN, out, DM, b_out, DIN);
}

// Round 5
// 152.162 us; speedup vs baseline: 1.6084x; 1.6084x over previous
//
#include <hip/hip_runtime.h>
#include <cstdint>

// ---------- types ----------
typedef unsigned short u16;
typedef __bf16 bf16;
typedef bf16 bf16x8 __attribute__((ext_vector_type(8)));
typedef float f32x4 __attribute__((ext_vector_type(4)));
typedef u16 u16x4 __attribute__((ext_vector_type(4)));
typedef u16 u16x8 __attribute__((ext_vector_type(8)));

#define B_SZ 4
#define L_SZ 1024
#define DM 512
#define DIN 1024
#define NST 16
#define RR 32
#define KC 4
#define NCHUNK 32
#define LC 32

__device__ __forceinline__ u16 f2bf(float f) {
  union { float f; uint32_t u; } v; v.f = f;
  uint32_t r = (v.u + 0x7FFFu + ((v.u >> 16) & 1u)) >> 16;
  return (u16)r;
}
__device__ __forceinline__ float bf2f(u16 h) {
  union { uint32_t u; float f; } v; v.u = ((uint32_t)h) << 16;
  return v.f;
}

// hardware 2^x (v_exp_f32)
__device__ __forceinline__ float exp2i(float x) {
#if __has_builtin(__builtin_amdgcn_exp2f)
  return __builtin_amdgcn_exp2f(x);
#else
  float r; asm("v_exp_f32 %0, %1" : "=v"(r) : "v"(x)); return r;
#endif
}

__device__ __forceinline__ void gload16(const void* g, void* l) {
  __builtin_amdgcn_global_load_lds(
      (const __attribute__((address_space(1))) unsigned int*)g,
      (__attribute__((address_space(3))) unsigned int*)l, 16, 0, 0);
}

// ---------- f32 -> bf16 convert ----------
__launch_bounds__(256)
__global__ void cvt_f2b(const float* __restrict__ in, u16* __restrict__ out, int n) {
  int i = (blockIdx.x * 256 + threadIdx.x) * 8;
  if (i >= n) return;
  f32x4 a = *(const f32x4*)(in + i);
  f32x4 b = *(const f32x4*)(in + i + 4);
  u16x8 o;
#pragma unroll
  for (int j = 0; j < 4; j++) { o[j] = f2bf(a[j]); o[4 + j] = f2bf(b[j]); }
  *(u16x8*)(out + i) = o;
}

// ---------- f32 (R x C) -> bf16 transpose (C x R) ----------
__global__ void transpose_f2b(const float* __restrict__ in, u16* __restrict__ out,
                              int R, int C) {
  __shared__ float tile[32][33];
  int tx = threadIdx.x, ty = threadIdx.y;
  int c0 = blockIdx.x * 32, r0 = blockIdx.y * 32;
#pragma unroll
  for (int i = 0; i < 4; i++)
    tile[ty + i * 8][tx] = in[(long)(r0 + ty + i * 8) * C + c0 + tx];
  __syncthreads();
#pragma unroll
  for (int i = 0; i < 4; i++)
    out[(long)(c0 + ty + i * 8) * R + r0 + tx] = f2bf(tile[tx][ty + i * 8]);
}

// ---------- templated bf16 MFMA GEMM: C = A(MxK) * Bt(NxK)^T ----------
// EPI 0: f32 out (+bias), 1: bf16 out, 2: softplus(acc+bias) f32 out
template <int BM, int BN, int BK, int EPI>
__launch_bounds__(256, 2)
__global__ void gemm_bf16(const bf16* __restrict__ A, int lda,
                          const bf16* __restrict__ Bt, int ldb,
                          void* __restrict__ Cv, int ldc,
                          const float* __restrict__ bias, int K) {
  constexpr int WM = BM / 2, WN = BN / 2;
  constexpr int MF = WM / 16, NF = WN / 16;
  constexpr int LPR = BK / 8;            // 16B lanes per tile row
  constexpr int AISS = (BM * BK * 2) / 4096;
  constexpr int BISS = (BN * BK * 2) / 4096;
  __shared__ bf16 As[BM * BK];
  __shared__ bf16 Bs[BN * BK];
  const int t = threadIdx.x;
  const int lane = t & 63;
  const int wid = t >> 6;
  const int wm = wid >> 1, wn = wid & 1;
  const int r = lane & 15, kg = lane >> 4;
  const long row0 = (long)blockIdx.x * BM, col0 = (long)blockIdx.y * BN;

  f32x4 acc[MF][NF];
#pragma unroll
  for (int m = 0; m < MF; m++)
#pragma unroll
    for (int n = 0; n < NF; n++) acc[m][n] = f32x4{0.f, 0.f, 0.f, 0.f};

  for (int k0 = 0; k0 < K; k0 += BK) {
    __syncthreads();
#pragma unroll
    for (int i = 0; i < AISS; i++) {
      int slot = i * 256 + t;
      int rw = slot / LPR, lc = slot % LPR;
      gload16(A + (row0 + rw) * lda + k0 + lc * 8,
              (char*)As + i * 4096 + wid * 1024);
    }
#pragma unroll
    for (int i = 0; i < BISS; i++) {
      int slot = i * 256 + t;
      int rw = slot / LPR, lc = slot % LPR;
      gload16(Bt + (col0 + rw) * ldb + k0 + lc * 8,
              (char*)Bs + i * 4096 + wid * 1024);
    }
    __syncthreads();
#pragma unroll
    for (int kk = 0; kk < BK / 32; kk++) {
      bf16x8 av[MF], bv[NF];
#pragma unroll
      for (int m = 0; m < MF; m++)
        av[m] = *(const bf16x8*)&As[(wm * WM + m * 16 + r) * BK + kk * 32 + kg * 8];
#pragma unroll
      for (int n = 0; n < NF; n++)
        bv[n] = *(const bf16x8*)&Bs[(wn * WN + n * 16 + r) * BK + kk * 32 + kg * 8];
#pragma unroll
      for (int m = 0; m < MF; m++)
#pragma unroll
        for (int n = 0; n < NF; n++)
          acc[m][n] = __builtin_amdgcn_mfma_f32_16x16x32_bf16(av[m], bv[n], acc[m][n], 0, 0, 0);
    }
  }

#pragma unroll
  for (int m = 0; m < MF; m++) {
    const long grow0 = row0 + wm * WM + m * 16 + kg * 4;
#pragma unroll
    for (int n = 0; n < NF; n++) {
      const long gcol = col0 + wn * WN + n * 16 + r;
      float bval = bias ? bias[gcol] : 0.f;
#pragma unroll
      for (int j = 0; j < 4; j++) {
        float v = acc[m][n][j] + bval;
        long idx = (grow0 + j) * ldc + gcol;
        if (EPI == 0) {
          ((float*)Cv)[idx] = v;
        } else if (EPI == 1) {
          ((u16*)Cv)[idx] = f2bf(v);
        } else {
          ((float*)Cv)[idx] = (v > 20.f) ? v : log1pf(__expf(v));
        }
      }
    }
  }
}

// ---------- depthwise causal conv (K=4) + SiLU ----------
__launch_bounds__(256)
__global__ void conv_silu_k(const u16* __restrict__ xr, const float* __restrict__ cw,
                            const float* __restrict__ cb, u16* __restrict__ u) {
  int tid = blockIdx.x * 256 + threadIdx.x;
  int dblk = tid & 127, row = tid >> 7;     // row = b*L + l
  int l = row & (L_SZ - 1);
  int d = dblk * 8;
  float xv[4][8];
#pragma unroll
  for (int k = 0; k < 4; k++) {
    int ls = l - 3 + k;
    if (ls < 0) {
#pragma unroll
      for (int j = 0; j < 8; j++) xv[k][j] = 0.f;
    } else {
      u16x8 vv = *(const u16x8*)(xr + (long)(row - 3 + k) * (2 * DIN) + d);
#pragma unroll
      for (int j = 0; j < 8; j++) xv[k][j] = bf2f(vv[j]);
    }
  }
  u16x8 ov;
#pragma unroll
  for (int j = 0; j < 8; j++) {
    f32x4 w = *(const f32x4*)(cw + (d + j) * 4);
    float acc = cb[d + j] + w[0] * xv[0][j] + w[1] * xv[1][j] + w[2] * xv[2][j] + w[3] * xv[3][j];
    float s = acc / (1.f + __expf(-acc));
    ov[j] = f2bf(s);
  }
  *(u16x8*)(u + (long)row * DIN + d) = ov;
}

// ---------- selective scan, chunked: thread = (b, chunk, d) ----------
// Each thread keeps ALL 16 n-state chains in registers: 16-way in-thread ILP
// makes the kernel issue-bound (not latency-bound). delta/u are read straight
// from global, perfectly coalesced (lane d reads element d of row l), with a
// 2-deep scalar prefetch. B/C rows (16 f32 each) live in a 4 KB LDS stage and
// are read per-l as wave-broadcast ds_read_b128 (conflict-free).
// Phase A (WITHY=0): local end state + P = exp2(An*sum(delta)).
// Phase C (WITHY=1): replay with true s_init; y = sum_n s[n]*C[n] in-thread;
// +u*D and silu(res) gating fused; emits bf16 GEMM4 input.
template <int WITHY>
__launch_bounds__(256, 2)
__global__ void scan_phase(const float* __restrict__ delta, const u16* __restrict__ u,
                           const u16* __restrict__ xdbl, const float* __restrict__ A_log,
                           const float* __restrict__ s_init, const float* __restrict__ Dvec,
                           const u16* __restrict__ xr,
                           float* __restrict__ S_end, float* __restrict__ P,
                           u16* __restrict__ yg) {
  const int bi = blockIdx.x;
  const int dblk = bi & 3, rem = bi >> 2;
  const int chunk = rem & (NCHUNK - 1), b = rem >> 5;
  const int t = threadIdx.x;
  const int d = dblk * 256 + t;
  const int l0 = chunk * LC;
  const float L2E = 1.44269504088896f;
  __shared__ float sB[LC][16];
  __shared__ float sC[WITHY ? LC : 1][16];
  {
    int row = t >> 3, g = t & 7;
    long rowb = (long)b * L_SZ + l0 + row;
    u16x4 v = *(const u16x4*)(xdbl + rowb * 64 + RR + g * 4);
    if (g < 4) {
#pragma unroll
      for (int j = 0; j < 4; j++) sB[row][g * 4 + j] = bf2f(v[j]);
    } else if constexpr (WITHY) {
#pragma unroll
      for (int j = 0; j < 4; j++) sC[row][(g - 4) * 4 + j] = bf2f(v[j]);
    }
  }
  float An[16];
#pragma unroll
  for (int q = 0; q < 4; q++) {
    f32x4 al = *(const f32x4*)(A_log + (long)d * NST + q * 4);
#pragma unroll
    for (int j = 0; j < 4; j++) An[q * 4 + j] = -__expf(al[j]) * L2E;
  }
  float s[16];
  const long sbase = ((long)(b * NCHUNK + chunk) * DIN + d) * NST;
  if constexpr (WITHY) {
#pragma unroll
    for (int q = 0; q < 4; q++) {
      f32x4 sv = *(const f32x4*)(s_init + sbase + q * 4);
#pragma unroll
      for (int j = 0; j < 4; j++) s[q * 4 + j] = sv[j];
    }
  } else {
#pragma unroll
    for (int n = 0; n < 16; n++) s[n] = 0.f;
  }
  float Dv = 0.f;
  if constexpr (WITHY) Dv = Dvec[d];
  __syncthreads();

  const long rowstep = DIN;
  const float* dptr = delta + ((long)b * L_SZ + l0) * DIN + d;
  const u16* uptr = u + ((long)b * L_SZ + l0) * DIN + d;
  const u16* rptr = xr + ((long)b * L_SZ + l0) * (2 * DIN) + DIN + d;
  u16* yptr = yg + ((long)b * L_SZ + l0) * DIN + d;

  float sde = 0.f;
  // 2-deep prefetch registers
  float deA = dptr[0], deB = dptr[rowstep];
  float uvA = bf2f(uptr[0]), uvB = bf2f(uptr[rowstep]);
  float rsA = 0.f, rsB = 0.f;
  if constexpr (WITHY) { rsA = bf2f(rptr[0]); rsB = bf2f(rptr[2 * DIN]); }

  auto step = [&](int i, float de, float uv, float rs) {
    float du = de * uv;
    f32x4 bq[4];
#pragma unroll
    for (int q = 0; q < 4; q++) bq[q] = *(const f32x4*)&sB[i][q * 4];
    if constexpr (WITHY) {
      f32x4 cq[4];
#pragma unroll
      for (int q = 0; q < 4; q++) cq[q] = *(const f32x4*)&sC[i][q * 4];
      float y0 = 0.f, y1 = 0.f, y2 = 0.f, y3 = 0.f;
#pragma unroll
      for (int q = 0; q < 4; q++)
#pragma unroll
        for (int j = 0; j < 4; j++) {
          int n = q * 4 + j;
          float a = exp2i(de * An[n]);
          s[n] = fmaf(a, s[n], du * bq[q][j]);
          float yy = s[n] * cq[q][j];
          if (q == 0) y0 += yy; else if (q == 1) y1 += yy;
          else if (q == 2) y2 += yy; else y3 += yy;
        }
      float y = (y0 + y1) + (y2 + y3);
      float sil = rs / (1.f + exp2i(-rs * L2E));
      yptr[(long)i * DIN] = f2bf(fmaf(uv, Dv, y) * sil);
    } else {
#pragma unroll
      for (int q = 0; q < 4; q++)
#pragma unroll
        for (int j = 0; j < 4; j++) {
          int n = q * 4 + j;
          float a = exp2i(de * An[n]);
          s[n] = fmaf(a, s[n], du * bq[q][j]);
        }
      sde += de;
    }
  };

  for (int i = 0; i < LC; i += 2) {
    float deN0 = 0.f, deN1 = 0.f, uvN0 = 0.f, uvN1 = 0.f, rsN0 = 0.f, rsN1 = 0.f;
    if (i + 2 < LC) {
      deN0 = dptr[(long)(i + 2) * rowstep];
      uvN0 = bf2f(uptr[(long)(i + 2) * rowstep]);
      if constexpr (WITHY) rsN0 = bf2f(rptr[(long)(i + 2) * 2 * DIN]);
      deN1 = dptr[(long)(i + 3) * rowstep];
      uvN1 = bf2f(uptr[(long)(i + 3) * rowstep]);
      if constexpr (WITHY) rsN1 = bf2f(rptr[(long)(i + 3) * 2 * DIN]);
    }
    step(i, deA, uvA, rsA);
    step(i + 1, deB, uvB, rsB);
    deA = deN0; uvA = uvN0; rsA = rsN0;
    deB = deN1; uvB = uvN1; rsB = rsN1;
  }

  if constexpr (!WITHY) {
#pragma unroll
    for (int q = 0; q < 4; q++) {
      f32x4 sv, pv;
#pragma unroll
      for (int j = 0; j < 4; j++) {
        sv[j] = s[q * 4 + j];
        pv[j] = exp2i(An[q * 4 + j] * sde);
      }
      *(f32x4*)(S_end + sbase + q * 4) = sv;
      *(f32x4*)(P + sbase + q * 4) = pv;
    }
  }
}

__launch_bounds__(256)
__global__ void scan_combine(const float* __restrict__ P, const float* __restrict__ S_end,
                             float* __restrict__ s_init) {
  int g = blockIdx.x * 256 + threadIdx.x;   // (b, d, n) : 4*1024*16
  int b = g >> 14, dn = g & 16383;
  long base = (long)b * (NCHUNK * DIN * NST) + dn;
  float s = 0.f;
#pragma unroll
  for (int c = 0; c < NCHUNK; c++) {
    long idx = base + (long)c * (DIN * NST);
    s_init[idx] = s;
    s = P[idx] * s + S_end[idx];
  }
}

// ---------- host ----------
extern "C" void kernel_launch(void* const* d_in, const int* in_sizes, int n_in,
                              void* d_out, int out_size, void* d_ws, size_t ws_size,
                              hipStream_t stream) {
  const float* x      = (const float*)d_in[0];
  const float* W_in   = (const float*)d_in[1];
  const float* conv_w = (const float*)d_in[2];
  const float* conv_b = (const float*)d_in[3];
  const float* W_x    = (const float*)d_in[4];
  const float* W_dt   = (const float*)d_in[5];
  const float* b_dt   = (const float*)d_in[6];
  const float* A_log  = (const float*)d_in[7];
  const float* Dvec   = (const float*)d_in[8];
  const float* W_out  = (const float*)d_in[9];
  const float* b_out  = (const float*)d_in[10];
  float* out = (float*)d_out;

  char* ws = (char*)d_ws;
  size_t off = 0;
  auto alloc = [&](size_t bytes) -> void* {
    void* p = ws + off;
    off += (bytes + 255) & ~(size_t)255;
    return p;
  };
  const int M = B_SZ * L_SZ;                  // 4096
  u16*   xw    = (u16*)alloc((size_t)M * DM * 2);
  u16*   winT  = (u16*)alloc((size_t)(2 * DIN) * DM * 2);
  u16*   xr    = (u16*)alloc((size_t)M * (2 * DIN) * 2);
  u16*   ubuf  = (u16*)alloc((size_t)M * DIN * 2);
  u16*   wxT   = (u16*)alloc((size_t)64 * DIN * 2);
  u16*   xdbl  = (u16*)alloc((size_t)M * 64 * 2);
  u16*   wdtT  = (u16*)alloc((size_t)DIN * RR * 2);
  float* delta = (float*)alloc((size_t)M * DIN * 4);
  float* Send  = (float*)alloc((size_t)B_SZ * NCHUNK * DIN * NST * 4);
  float* Pbuf  = (float*)alloc((size_t)B_SZ * NCHUNK * DIN * NST * 4);
  float* sini  = (float*)alloc((size_t)B_SZ * NCHUNK * DIN * NST * 4);
  u16*   yg    = (u16*)alloc((size_t)M * DIN * 2);
  u16*   woutT = (u16*)alloc((size_t)DM * DIN * 2);
  (void)ws_size; (void)in_sizes; (void)n_in; (void)out_size;

  // convert x to bf16
  cvt_f2b<<<(M * DM) / (256 * 8), 256, 0, stream>>>(x, xw, M * DM);
  // transpose weights to (N x K) bf16
  transpose_f2b<<<dim3((2 * DIN) / 32, DM / 32), dim3(32, 8), 0, stream>>>(W_in, winT, DM, 2 * DIN);
  transpose_f2b<<<dim3(64 / 32, DIN / 32), dim3(32, 8), 0, stream>>>(W_x, wxT, DIN, 64);
  transpose_f2b<<<dim3(DIN / 32, RR / 32), dim3(32, 8), 0, stream>>>(W_dt, wdtT, RR, DIN);
  transpose_f2b<<<dim3(DM / 32, DIN / 32), dim3(32, 8), 0, stream>>>(W_out, woutT, DIN, DM);

  // GEMM1: x_and_res = x @ W_in   (4096 x 2048, K=512) -> bf16
  gemm_bf16<128, 128, 64, 1><<<dim3(M / 128, (2 * DIN) / 128), 256, 0, stream>>>(
      (const bf16*)xw, DM, (const bf16*)winT, DM, xr, 2 * DIN, nullptr, DM);
  // conv + silu -> u (bf16)
  conv_silu_k<<<(M * DIN / 8) / 256, 256, 0, stream>>>(xr, conv_w, conv_b, ubuf);
  // GEMM2: x_dbl = u @ W_x  (4096 x 64, K=1024) -> bf16  (BM=32: 128 blocks)
  gemm_bf16<32, 64, 64, 1><<<dim3(M / 32, 1), 256, 0, stream>>>(
      (const bf16*)ubuf, DIN, (const bf16*)wxT, DIN, xdbl, 64, nullptr, DIN);
  // GEMM3: delta = softplus(x_dbl[:, :32] @ W_dt + b_dt) (4096 x 1024, K=32) -> f32
  gemm_bf16<128, 128, 32, 2><<<dim3(M / 128, DIN / 128), 256, 0, stream>>>(
      (const bf16*)xdbl, 64, (const bf16*)wdtT, RR, delta, DIN, b_dt, RR);
  // scan: 512 blocks each, thread = (b, chunk, d)
  scan_phase<0><<<B_SZ * NCHUNK * (DIN / 256), 256, 0, stream>>>(
      delta, ubuf, xdbl, A_log, nullptr, nullptr, xr, Send, Pbuf, yg);
  scan_combine<<<(B_SZ * DIN * NST) / 256, 256, 0, stream>>>(Pbuf, Send, sini);
  scan_phase<1><<<B_SZ * NCHUNK * (DIN / 256), 256, 0, stream>>>(
      delta, ubuf, xdbl, A_log, sini, Dvec, xr, nullptr, nullptr, yg);
  // GEMM4: out = (y * silu(res)) @ W_out + b_out  (4096 x 512, K=1024) -> f32
  gemm_bf16<128, 64, 64, 0><<<dim3(M / 128, DM / 64), 256, 0, stream>>>(
      (const bf16*)yg, DIN, (const bf16*)woutT, DIN, out, DM, b_out, DIN);
}